// Round 9
// baseline (352.923 us; speedup 1.0000x reference)
//
#include <hip/hip_runtime.h>

typedef unsigned short u16;
typedef unsigned int u32;
typedef __attribute__((ext_vector_type(8))) short bf16x8;
typedef __attribute__((ext_vector_type(4))) float f32x4;

typedef __attribute__((address_space(1))) const unsigned int gu32;
typedef __attribute__((address_space(3))) unsigned int lu32;

#define FMIN32 -3.402823466e38f

__device__ inline u16 f2bf(float f) {
    u32 x = __float_as_uint(f);
    u32 r = x + 0x7FFFu + ((x >> 16) & 1u);
    return (u16)(r >> 16);
}
__device__ inline float bf2f(u16 u) { return __uint_as_float(((u32)u) << 16); }

__device__ inline double wave_sum_d(double v) {
#pragma unroll
    for (int m = 1; m < 64; m <<= 1) v += __shfl_xor(v, m, 64);
    return v;
}

// ---------------- weight conversion: W[k][n] fp32 -> Wt[n][k] bf16 ----------------
__global__ __launch_bounds__(256) void convert_w(const float* W0, const float* W1,
                                                 const float* W2, const float* W3, u16* Wt) {
    const float* Ws[4] = {W0, W1, W2, W3};
    int z = blockIdx.z;
    const float* W = Ws[z];
    u16* O = Wt + (size_t)z * 65536;
    __shared__ float tl[32][33];
    int t = threadIdx.x;
    int bx = blockIdx.x, by = blockIdx.y;
#pragma unroll
    for (int i = 0; i < 4; i++) {
        int e = i * 256 + t; int tr = e >> 5, tc = e & 31;
        tl[tr][tc] = W[(size_t)(bx * 32 + tr) * 256 + by * 32 + tc];
    }
    __syncthreads();
#pragma unroll
    for (int i = 0; i < 4; i++) {
        int e = i * 256 + t; int tr = e >> 5, tc = e & 31;
        O[(size_t)(by * 32 + tr) * 256 + bx * 32 + tc] = f2bf(tl[tc][tr]);
    }
}

// fc_bin[p][c'][o] fp32 -> fcT[p][o][c'] bf16   (c'=1024, o=256)
__global__ __launch_bounds__(256) void convert_fc(const float* F, u16* O) {
    int p = blockIdx.z;
    int bx = blockIdx.x, by = blockIdx.y;
    const float* Fp = F + (size_t)p * 1024 * 256;
    u16* Op = O + (size_t)p * 256 * 1024;
    __shared__ float tl[32][33];
    int t = threadIdx.x;
#pragma unroll
    for (int i = 0; i < 4; i++) {
        int e = i * 256 + t; int tr = e >> 5, tc = e & 31;
        tl[tr][tc] = Fp[(size_t)(bx * 32 + tr) * 256 + by * 32 + tc];
    }
    __syncthreads();
#pragma unroll
    for (int i = 0; i < 4; i++) {
        int e = i * 256 + t; int tr = e >> 5, tc = e & 31;
        Op[(size_t)(by * 32 + tr) * 1024 + bx * 32 + tc] = f2bf(tl[tc][tr]);
    }
}

// ---------------- x (n,c,s,p) fp32 -> xt (n*16+p, s, c) fp32 + bf16 ----------------
__global__ __launch_bounds__(256) void transpose_x(const float* x, float* xt, u16* xtbf) {
    int bx = blockIdx.x;
    int nn = bx >> 6, s = bx & 63;
    __shared__ float tile[16][257];
    int t = threadIdx.x;
    const float* xb = x + (size_t)nn * 262144 + (size_t)s * 16;
#pragma unroll
    for (int chunk = 0; chunk < 16; chunk++) {
        int e = chunk * 256 + t;
        int c = e >> 4, pp = e & 15;
        tile[pp][c] = xb[(size_t)c * 1024 + pp];
    }
    __syncthreads();
#pragma unroll
    for (int pp = 0; pp < 16; pp++) {
        float v = tile[pp][t];
        size_t o = ((size_t)(nn * 16 + pp) * 64 + s) * 256 + t;
        xt[o] = v;
        xtbf[o] = f2bf(v);
    }
}

// ---------------- instance norm + cosine sim + argmax (float64, LDS-staged) ----------------
__global__ __launch_bounds__(256) void norm_sim(const float* xt, const float* prot, int* hard) {
    int b = blockIdx.x;
    int pp = b & 15, nn = b >> 4;
    __shared__ float xs[64][257];
    __shared__ double wk[4][256];
    __shared__ double smu[256];
    __shared__ double srstd[256];
    __shared__ double offk[4];
    __shared__ double dd[64][5];
    int t = threadIdx.x, w = t >> 6, lane = t & 63;

    const float* xb = xt + (size_t)b * 64 * 256 + t;
    double s1 = 0.0, s2 = 0.0;
#pragma unroll 8
    for (int s = 0; s < 64; s++) {
        float v = xb[(size_t)s * 256];
        xs[s][t] = v;
        double dv = (double)v;
        s1 += dv; s2 += dv * dv;
    }
    double mu = s1 * (1.0 / 64.0);
    double var = s2 * (1.0 / 64.0) - mu * mu;
    smu[t] = mu;
    srstd[t] = 1.0 / sqrt(var + 1e-5);
    __syncthreads();

    {
        double pv[4]; double ss = 0.0;
#pragma unroll
        for (int j = 0; j < 4; j++) {
            pv[j] = (double)prot[((size_t)pp * 4 + w) * 256 + lane + 64 * j];
            ss += pv[j] * pv[j];
        }
        ss = wave_sum_d(ss);
        double rn = 1.0 / sqrt(ss);
        double po = 0.0;
#pragma unroll
        for (int j = 0; j < 4; j++) {
            int c = lane + 64 * j;
            double wv = pv[j] * rn * srstd[c];
            wk[w][c] = wv;
            po += wv * smu[c];
        }
        po = wave_sum_d(po);
        if (lane == 0) offk[w] = po;
    }
    __syncthreads();

    {
        int s = lane;
        const float* xr = &xs[s][0];
        const double* wr = &wk[w][0];
        double a0 = 0.0, a1 = 0.0, a2 = 0.0, a3 = 0.0;
#pragma unroll 8
        for (int c = 0; c < 256; c += 4) {
            a0 = fma((double)xr[c],     wr[c],     a0);
            a1 = fma((double)xr[c + 1], wr[c + 1], a1);
            a2 = fma((double)xr[c + 2], wr[c + 2], a2);
            a3 = fma((double)xr[c + 3], wr[c + 3], a3);
        }
        dd[s][w] = ((a0 + a1) + (a2 + a3)) - offk[w];
    }
    __syncthreads();

    if (t < 64) {
        double d0 = dd[t][0], d1 = dd[t][1], d2 = dd[t][2], d3 = dd[t][3];
        int best = 0; double bv = d0;
        if (d1 > bv) { bv = d1; best = 1; }
        if (d2 > bv) { bv = d2; best = 2; }
        if (d3 > bv) { best = 3; }
        hard[((pp * 64 + nn) << 6) + t] = best;
    }
}

// ---------------- mode over parts -> cluster_indices (fp32 out) ----------------
__global__ __launch_bounds__(256) void cluster_mode(const int* hard, float* outp) {
    int tid = blockIdx.x * 256 + threadIdx.x;
    int nn = tid >> 6, s = tid & 63;
    int cnt[4] = {0, 0, 0, 0};
#pragma unroll
    for (int p = 0; p < 16; p++) cnt[hard[((p * 64 + nn) << 6) + s]]++;
    int best = 0;
#pragma unroll
    for (int k = 1; k < 4; k++) if (cnt[k] > cnt[best]) best = k;
    outp[tid] = (float)best;
}

// ======== MEGA-FUSED (8-wave): QKV + causal attention + Wo + residual + scatter-max ========
// One block per batch b, 512 threads. Wave = (head w, M-half h). LDS 71 KB -> 2 blocks/CU
// = 16 waves/CU = 4 waves/SIMD. __launch_bounds__(512,2) -> VGPR cap >=128 (round-8's
// (512,4) capped at 64 and spilled ~50 dwords/thread to scratch: +95 MB HBM traffic).
__global__ __launch_bounds__(512, 2) void fused_attn(const u16* xtbf, const u16* Wt,
                                                  const float* bq, const float* bk, const float* bv,
                                                  const float* bo, const int* hard, u16* clus) {
    __shared__ u16 xs[64][264];     // x2[b] bf16; stride 264 u16: conflict-free b128
    __shared__ u16 scr[4][64][72];  // per-head scratch; stride 72 u16 = 9*16B
    __shared__ int sidx[64];
    int t = threadIdx.x;
    int W = t >> 6;                 // wave 0..7
    int w = W & 3;                  // head
    int h = W >> 2;                 // M-half
    int rb = h * 32;                // row base of this wave's half
    int lane = t & 63;
    int l15 = lane & 15, qd = lane >> 4;
    int b = blockIdx.x;
    int pp = b & 15, nn = b >> 4;

    // stage x tile + cluster indices
    {
        const u16* xb = xtbf + (size_t)b * 16384;
#pragma unroll
        for (int i = 0; i < 4; i++) {
            int e = i * 512 + t;
            int r = e >> 5, g = e & 31;
            *(uint4*)&xs[r][g * 8] = *(const uint4*)(xb + (size_t)r * 256 + g * 8);
        }
        if (t < 64) sidx[t] = hard[((pp * 64 + nn) << 6) + t];
    }
    __syncthreads();   // B1: xs + sidx visible

    const f32x4 zero4 = {0.f, 0.f, 0.f, 0.f};
    u16* sw = &scr[w][0][0];

    // ---- Q and K gemms interleaved (rows rb..rb+31): shared A-frags ----
    f32x4 accQ[2][4], accK[2][4];
#pragma unroll
    for (int mt = 0; mt < 2; mt++)
#pragma unroll
        for (int nt = 0; nt < 4; nt++) { accQ[mt][nt] = zero4; accK[mt][nt] = zero4; }
    {
        const u16* WQ = Wt + (size_t)(w * 64) * 256;
        const u16* WK = WQ + 65536;
#pragma unroll
        for (int kc = 0; kc < 8; kc++) {
            bf16x8 af[2], bq4[4], bk4[4];
#pragma unroll
            for (int mt = 0; mt < 2; mt++)
                af[mt] = *(const bf16x8*)(&xs[rb + mt * 16 + l15][kc * 32 + qd * 8]);
#pragma unroll
            for (int nt = 0; nt < 4; nt++) {
                bq4[nt] = *(const bf16x8*)(WQ + (size_t)(nt * 16 + l15) * 256 + kc * 32 + qd * 8);
                bk4[nt] = *(const bf16x8*)(WK + (size_t)(nt * 16 + l15) * 256 + kc * 32 + qd * 8);
            }
#pragma unroll
            for (int mt = 0; mt < 2; mt++)
#pragma unroll
                for (int nt = 0; nt < 4; nt++) {
                    accQ[mt][nt] = __builtin_amdgcn_mfma_f32_16x16x32_bf16(af[mt], bq4[nt], accQ[mt][nt], 0, 0, 0);
                    accK[mt][nt] = __builtin_amdgcn_mfma_f32_16x16x32_bf16(af[mt], bk4[nt], accK[mt][nt], 0, 0, 0);
                }
        }
    }

    // ---- repack Q (own rows) -> qf ----
    bf16x8 qf[2][2], kf[2][4];
#pragma unroll
    for (int mt = 0; mt < 2; mt++)
#pragma unroll
        for (int nt = 0; nt < 4; nt++) {
            int col = nt * 16 + l15;
            float bb = bq[w * 64 + col];
#pragma unroll
            for (int r = 0; r < 4; r++)
                sw[(rb + mt * 16 + qd * 4 + r) * 72 + col] = f2bf(accQ[mt][nt][r] + bb);
        }
#pragma unroll
    for (int kc2 = 0; kc2 < 2; kc2++)
#pragma unroll
        for (int mt = 0; mt < 2; mt++)
            qf[kc2][mt] = *(const bf16x8*)(sw + (rb + mt * 16 + l15) * 72 + kc2 * 32 + qd * 8);

    // ---- repack K (own rows) ----
#pragma unroll
    for (int mt = 0; mt < 2; mt++)
#pragma unroll
        for (int nt = 0; nt < 4; nt++) {
            int col = nt * 16 + l15;
            float bb = bk[w * 64 + col];
#pragma unroll
            for (int r = 0; r < 4; r++)
                sw[(rb + mt * 16 + qd * 4 + r) * 72 + col] = f2bf(accK[mt][nt][r] + bb);
        }
    __syncthreads();   // B2: both halves' K rows in scr
#pragma unroll
    for (int kc2 = 0; kc2 < 2; kc2++)
#pragma unroll
        for (int nt = 0; nt < 4; nt++)
            kf[kc2][nt] = *(const bf16x8*)(sw + (nt * 16 + l15) * 72 + kc2 * 32 + qd * 8);

    // ---- S = Q K^T (rows own, cols all) ----
    f32x4 accS[2][4];
#pragma unroll
    for (int mt = 0; mt < 2; mt++)
#pragma unroll
        for (int nt = 0; nt < 4; nt++) accS[mt][nt] = zero4;
#pragma unroll
    for (int kc2 = 0; kc2 < 2; kc2++)
#pragma unroll
        for (int mt = 0; mt < 2; mt++)
#pragma unroll
            for (int nt = 0; nt < 4; nt++)
                accS[mt][nt] = __builtin_amdgcn_mfma_f32_16x16x32_bf16(qf[kc2][mt], kf[kc2][nt], accS[mt][nt], 0, 0, 0);

    // ---- V gemm (independent; overlaps softmax below) ----
    f32x4 accV[2][4];
#pragma unroll
    for (int mt = 0; mt < 2; mt++)
#pragma unroll
        for (int nt = 0; nt < 4; nt++) accV[mt][nt] = zero4;
    {
        const u16* WV = Wt + 2 * 65536 + (size_t)(w * 64) * 256;
#pragma unroll
        for (int kc = 0; kc < 8; kc++) {
            bf16x8 af[2], bv4[4];
#pragma unroll
            for (int mt = 0; mt < 2; mt++)
                af[mt] = *(const bf16x8*)(&xs[rb + mt * 16 + l15][kc * 32 + qd * 8]);
#pragma unroll
            for (int nt = 0; nt < 4; nt++)
                bv4[nt] = *(const bf16x8*)(WV + (size_t)(nt * 16 + l15) * 256 + kc * 32 + qd * 8);
#pragma unroll
            for (int mt = 0; mt < 2; mt++)
#pragma unroll
                for (int nt = 0; nt < 4; nt++)
                    accV[mt][nt] = __builtin_amdgcn_mfma_f32_16x16x32_bf16(af[mt], bv4[nt], accV[mt][nt], 0, 0, 0);
        }
    }
    __syncthreads();   // B3: all waves done reading K rows (kf) -> P stores may overwrite

    // ---- causal mask + softmax on accS -> P (own rows) ----
#pragma unroll
    for (int mt = 0; mt < 2; mt++) {
#pragma unroll
        for (int r = 0; r < 4; r++) {
            int row = rb + mt * 16 + qd * 4 + r;
            float v[4];
#pragma unroll
            for (int nt = 0; nt < 4; nt++) {
                int col = nt * 16 + l15;
                float sv = accS[mt][nt][r] * 0.125f;
                if (col > row) sv = FMIN32;
                v[nt] = sv;
            }
            float m = fmaxf(fmaxf(v[0], v[1]), fmaxf(v[2], v[3]));
#pragma unroll
            for (int msk = 1; msk < 16; msk <<= 1) m = fmaxf(m, __shfl_xor(m, msk, 64));
            float e[4], ssum = 0.f;
#pragma unroll
            for (int nt = 0; nt < 4; nt++) { e[nt] = expf(v[nt] - m); ssum += e[nt]; }
#pragma unroll
            for (int msk = 1; msk < 16; msk <<= 1) ssum += __shfl_xor(ssum, msk, 64);
            float rinv = 1.0f / ssum;
#pragma unroll
            for (int nt = 0; nt < 4; nt++) sw[row * 72 + nt * 16 + l15] = f2bf(e[nt] * rinv);
        }
    }
    bf16x8 pf[2][2];
#pragma unroll
    for (int kc2 = 0; kc2 < 2; kc2++)
#pragma unroll
        for (int mt = 0; mt < 2; mt++)
            pf[kc2][mt] = *(const bf16x8*)(sw + (rb + mt * 16 + l15) * 72 + kc2 * 32 + qd * 8);
    __syncthreads();   // B4: all pf loaded -> V^T stores may overwrite P region

    // ---- V^T repack (accV + bias) -> scr [d][s] (all rows, own cols) ----
#pragma unroll
    for (int mt = 0; mt < 2; mt++)
#pragma unroll
        for (int nt = 0; nt < 4; nt++) {
            int d = nt * 16 + l15;
            float bb = bv[w * 64 + d];
            ushort4 pk;
            pk.x = f2bf(accV[mt][nt][0] + bb);
            pk.y = f2bf(accV[mt][nt][1] + bb);
            pk.z = f2bf(accV[mt][nt][2] + bb);
            pk.w = f2bf(accV[mt][nt][3] + bb);
            *(ushort4*)(sw + d * 72 + rb + mt * 16 + qd * 4) = pk;
        }
    __syncthreads();   // B5: full V^T available
    bf16x8 vf[2][4];
#pragma unroll
    for (int kc2 = 0; kc2 < 2; kc2++)
#pragma unroll
        for (int nt = 0; nt < 4; nt++)
            vf[kc2][nt] = *(const bf16x8*)(sw + (nt * 16 + l15) * 72 + kc2 * 32 + qd * 8);
    __syncthreads();   // B6: all vf loaded -> O stores may overwrite

    // ---- O = P @ V (rows own) ----
    f32x4 acc[2][4];
#pragma unroll
    for (int mt = 0; mt < 2; mt++)
#pragma unroll
        for (int nt = 0; nt < 4; nt++) acc[mt][nt] = zero4;
#pragma unroll
    for (int kc2 = 0; kc2 < 2; kc2++)
#pragma unroll
        for (int nt = 0; nt < 4; nt++)
#pragma unroll
            for (int mt = 0; mt < 2; mt++)
                acc[mt][nt] = __builtin_amdgcn_mfma_f32_16x16x32_bf16(pf[kc2][mt], vf[kc2][nt], acc[mt][nt], 0, 0, 0);

    // ---- O head (own rows) -> scratch [q][d] bf16 ----
#pragma unroll
    for (int mt = 0; mt < 2; mt++)
#pragma unroll
        for (int nt = 0; nt < 4; nt++)
#pragma unroll
            for (int r = 0; r < 4; r++)
                sw[(rb + mt * 16 + qd * 4 + r) * 72 + nt * 16 + l15] = f2bf(acc[mt][nt][r]);
    __syncthreads();   // B7: all O written

    // ---- Wo gemm: rows own half, out cols w*64..; A = O concat from 4 scratches ----
    {
        const u16* WO = Wt + 3 * 65536 + (size_t)(w * 64) * 256;
#pragma unroll
        for (int mt = 0; mt < 2; mt++)
#pragma unroll
            for (int nt = 0; nt < 4; nt++) acc[mt][nt] = zero4;
#pragma unroll
        for (int kc = 0; kc < 8; kc++) {
            int hh = kc >> 1, k2 = kc & 1;
            bf16x8 af[2], bfr[4];
#pragma unroll
            for (int mt = 0; mt < 2; mt++)
                af[mt] = *(const bf16x8*)(&scr[hh][rb + mt * 16 + l15][k2 * 32 + qd * 8]);
#pragma unroll
            for (int nt = 0; nt < 4; nt++)
                bfr[nt] = *(const bf16x8*)(WO + (size_t)(nt * 16 + l15) * 256 + kc * 32 + qd * 8);
#pragma unroll
            for (int mt = 0; mt < 2; mt++)
#pragma unroll
                for (int nt = 0; nt < 4; nt++)
                    acc[mt][nt] = __builtin_amdgcn_mfma_f32_16x16x32_bf16(af[mt], bfr[nt], acc[mt][nt], 0, 0, 0);
        }
    }

    // ---- epilogue: +bias +residual (xs), per-half grouped max, cross-half combine ----
#pragma unroll
    for (int mt = 0; mt < 2; mt++)
#pragma unroll
        for (int nt = 0; nt < 4; nt++) {
            int col = w * 64 + nt * 16 + l15;
            float bb = bo[col];
#pragma unroll
            for (int r = 0; r < 4; r++) {
                int s = rb + mt * 16 + qd * 4 + r;
                acc[mt][nt][r] += bb + bf2f(xs[s][col]);
            }
        }
    int myidx = sidx[lane];
    u32 sr0 = 0;   // 8 nibble cluster-ids for this lane's rows
#pragma unroll
    for (int mt = 0; mt < 2; mt++)
#pragma unroll
        for (int r = 0; r < 4; r++)
            sr0 |= ((u32)sidx[rb + mt * 16 + qd * 4 + r]) << ((mt * 4 + r) * 4);

    float* pbuf = (float*)(&scr[0][0][0]);   // 2 halves x 4 k x 256 cols = 8KB (scr dead after B8)
    float pm[4][4];   // [k][nt] this wave's partial max
    int ckk[4];
#pragma unroll
    for (int k = 0; k < 4; k++) {
        unsigned long long bal = __ballot(myidx == k);
        ckk[k] = __popcll(bal);
        float m0 = FMIN32, m1 = FMIN32, m2 = FMIN32, m3 = FMIN32;
#pragma unroll
        for (int mt = 0; mt < 2; mt++)
#pragma unroll
            for (int r = 0; r < 4; r++) {
                u32 kk = (sr0 >> ((mt * 4 + r) * 4)) & 15u;
                bool tk = (kk == (u32)k);
                m0 = tk ? fmaxf(m0, acc[mt][0][r]) : m0;
                m1 = tk ? fmaxf(m1, acc[mt][1][r]) : m1;
                m2 = tk ? fmaxf(m2, acc[mt][2][r]) : m2;
                m3 = tk ? fmaxf(m3, acc[mt][3][r]) : m3;
            }
        float mm[4] = {m0, m1, m2, m3};
#pragma unroll
        for (int nt = 0; nt < 4; nt++) {
            float m = mm[nt];
            m = fmaxf(m, __shfl_xor(m, 16, 64));
            m = fmaxf(m, __shfl_xor(m, 32, 64));
            if (ckk[k] < 64) m = fmaxf(m, 0.0f);
            pm[k][nt] = m;
        }
    }
    __syncthreads();   // B8: Wo reads of scr complete -> reuse as pbuf
#pragma unroll
    for (int k = 0; k < 4; k++)
#pragma unroll
        for (int nt = 0; nt < 4; nt++)
            if (qd == 0) pbuf[(h * 4 + k) * 256 + w * 64 + nt * 16 + l15] = pm[k][nt];
    __syncthreads();   // B9: partials visible
    if (h == 0) {
        size_t ob = ((size_t)(pp * 64 + nn)) * 1024;
#pragma unroll
        for (int k = 0; k < 4; k++)
#pragma unroll
            for (int nt = 0; nt < 4; nt++) {
                int col = w * 64 + nt * 16 + l15;
                float m = fmaxf(pbuf[k * 256 + col], pbuf[(4 + k) * 256 + col]);
                if (qd == 0) clus[ob + k * 256 + col] = f2bf(m);
            }
    }
}

// ---- MFMA SeparateFCs, K-split: partial[kz][n][o][p] over kz chunks of 256 ----
__global__ __launch_bounds__(256) void gemm_fc_mfma(const u16* clus, const u16* fcT, float* part) {
    int p = blockIdx.x, by = blockIdx.y, kz = blockIdx.z;
    __shared__ u16 As[64 * 32];
    __shared__ u16 Bs[64 * 32];
    const u16* Ap = clus + (size_t)p * 65536 + kz * 256;
    const u16* Bp = fcT + (size_t)p * 262144 + (size_t)(by * 64) * 1024 + kz * 256;
    int t = threadIdx.x;
    int w = t >> 6, lane = t & 63;
    int l15 = lane & 15, qd = lane >> 4;
    f32x4 acc[4] = {};
    int srow = t >> 2, scg = t & 3;
    for (int kc = 0; kc < 256; kc += 32) {
        *(uint4*)(As + srow * 32 + scg * 8) =
            *(const uint4*)(Ap + (size_t)srow * 1024 + kc + scg * 8);
        *(uint4*)(Bs + srow * 32 + scg * 8) =
            *(const uint4*)(Bp + (size_t)srow * 1024 + kc + scg * 8);
        __syncthreads();
        bf16x8 bfr = *(const bf16x8*)(Bs + (w * 16 + l15) * 32 + qd * 8);
#pragma unroll
        for (int mt = 0; mt < 4; mt++) {
            bf16x8 af = *(const bf16x8*)(As + (mt * 16 + l15) * 32 + qd * 8);
            acc[mt] = __builtin_amdgcn_mfma_f32_16x16x32_bf16(af, bfr, acc[mt], 0, 0, 0);
        }
        __syncthreads();
    }
#pragma unroll
    for (int mt = 0; mt < 4; mt++)
#pragma unroll
        for (int r = 0; r < 4; r++) {
            int n = mt * 16 + qd * 4 + r;
            int o = by * 64 + w * 16 + l15;
            part[(size_t)kz * 262144 + (size_t)n * 4096 + (size_t)o * 16 + p] = acc[mt][r];
        }
}

// ---- sum 4 K-partials -> out_fc (float4 vectorized) ----
__global__ __launch_bounds__(256) void reduce_fc(const float* part, float* out) {
    int tid = blockIdx.x * 256 + threadIdx.x;
    const float4* p0 = (const float4*)part;
    float4 a = p0[tid];
    float4 b = p0[65536 + tid];
    float4 c = p0[131072 + tid];
    float4 d = p0[196608 + tid];
    float4 r;
    r.x = a.x + b.x + c.x + d.x;
    r.y = a.y + b.y + c.y + d.y;
    r.z = a.z + b.z + c.z + d.z;
    r.w = a.w + b.w + c.w + d.w;
    ((float4*)out)[tid] = r;
}

extern "C" void kernel_launch(void* const* d_in, const int* in_sizes, int n_in,
                              void* d_out, int out_size, void* d_ws, size_t ws_size,
                              hipStream_t stream) {
    const float* x    = (const float*)d_in[0];
    const float* prot = (const float*)d_in[1];
    const float* Wq   = (const float*)d_in[2];
    const float* bq   = (const float*)d_in[3];
    const float* Wk   = (const float*)d_in[4];
    const float* bk   = (const float*)d_in[5];
    const float* Wv   = (const float*)d_in[6];
    const float* bv   = (const float*)d_in[7];
    const float* Wo   = (const float*)d_in[8];
    const float* bo   = (const float*)d_in[9];
    const float* fcb  = (const float*)d_in[10];

    // Workspace map:
    //   [0,      33.5M)  xtbf bf16
    //   [33.5M, 100.7M)  xt fp32 (dead after norm_sim) -> fcpart (4 MB) reuses this
    //   [134.2M,+0.5M )  Wt bf16
    //   [134.7M,+8.4M )  fcT bf16
    //   [143.1M,+0.26M)  hard int32
    //   [143.4M,+2.1M )  clus bf16
    char* ws = (char*)d_ws;
    u16*   xtbf = (u16*)(ws + 0);
    float* xt   = (float*)(ws + 33554432);
    float* fcpart = (float*)(ws + 33554432);
    u16*   Wt   = (u16*)(ws + 134217728);
    u16*   fcT  = (u16*)(ws + 134742016);
    int*   hard = (int*)(ws + 143130624);
    u16*   clus = (u16*)(ws + 143392768);

    float* out_fc = (float*)d_out;
    float* out_ci = (float*)d_out + 262144;

    dim3 B(256);
    convert_w<<<dim3(8, 8, 4), B, 0, stream>>>(Wq, Wk, Wv, Wo, Wt);
    convert_fc<<<dim3(32, 8, 16), B, 0, stream>>>(fcb, fcT);
    transpose_x<<<dim3(4096), B, 0, stream>>>(x, xt, xtbf);
    norm_sim<<<dim3(1024), B, 0, stream>>>(xt, prot, hard);
    cluster_mode<<<dim3(16), B, 0, stream>>>(hard, out_ci);
    fused_attn<<<dim3(1024), dim3(512), 0, stream>>>(xtbf, Wt, bq, bk, bv, bo, hard, clus);
    gemm_fc_mfma<<<dim3(16, 4, 4), B, 0, stream>>>(clus, fcT, fcpart);
    reduce_fc<<<dim3(256), B, 0, stream>>>(fcpart, out_fc);
}

// Round 10
// 282.116 us; speedup vs baseline: 1.2510x; 1.2510x over previous
//
#include <hip/hip_runtime.h>

typedef unsigned short u16;
typedef unsigned int u32;
typedef __attribute__((ext_vector_type(8))) short bf16x8;
typedef __attribute__((ext_vector_type(4))) float f32x4;

typedef __attribute__((address_space(1))) const unsigned int gu32;
typedef __attribute__((address_space(3))) unsigned int lu32;

#define FMIN32 -3.402823466e38f

__device__ inline u16 f2bf(float f) {
    u32 x = __float_as_uint(f);
    u32 r = x + 0x7FFFu + ((x >> 16) & 1u);
    return (u16)(r >> 16);
}
__device__ inline float bf2f(u16 u) { return __uint_as_float(((u32)u) << 16); }

__device__ inline double wave_sum_d(double v) {
#pragma unroll
    for (int m = 1; m < 64; m <<= 1) v += __shfl_xor(v, m, 64);
    return v;
}

// ---------------- weight conversion: W[k][n] fp32 -> Wt[n][k] bf16 ----------------
__global__ __launch_bounds__(256) void convert_w(const float* W0, const float* W1,
                                                 const float* W2, const float* W3, u16* Wt) {
    const float* Ws[4] = {W0, W1, W2, W3};
    int z = blockIdx.z;
    const float* W = Ws[z];
    u16* O = Wt + (size_t)z * 65536;
    __shared__ float tl[32][33];
    int t = threadIdx.x;
    int bx = blockIdx.x, by = blockIdx.y;
#pragma unroll
    for (int i = 0; i < 4; i++) {
        int e = i * 256 + t; int tr = e >> 5, tc = e & 31;
        tl[tr][tc] = W[(size_t)(bx * 32 + tr) * 256 + by * 32 + tc];
    }
    __syncthreads();
#pragma unroll
    for (int i = 0; i < 4; i++) {
        int e = i * 256 + t; int tr = e >> 5, tc = e & 31;
        O[(size_t)(by * 32 + tr) * 256 + bx * 32 + tc] = f2bf(tl[tc][tr]);
    }
}

// fc_bin[p][c'][o] fp32 -> fcT[p][o][c'] bf16   (c'=1024, o=256)
__global__ __launch_bounds__(256) void convert_fc(const float* F, u16* O) {
    int p = blockIdx.z;
    int bx = blockIdx.x, by = blockIdx.y;
    const float* Fp = F + (size_t)p * 1024 * 256;
    u16* Op = O + (size_t)p * 256 * 1024;
    __shared__ float tl[32][33];
    int t = threadIdx.x;
#pragma unroll
    for (int i = 0; i < 4; i++) {
        int e = i * 256 + t; int tr = e >> 5, tc = e & 31;
        tl[tr][tc] = Fp[(size_t)(bx * 32 + tr) * 256 + by * 32 + tc];
    }
    __syncthreads();
#pragma unroll
    for (int i = 0; i < 4; i++) {
        int e = i * 256 + t; int tr = e >> 5, tc = e & 31;
        Op[(size_t)(by * 32 + tr) * 1024 + bx * 32 + tc] = f2bf(tl[tc][tr]);
    }
}

// ---- x (n,c,s,p) fp32 -> xt (n*16+p, s, c) fp32 + bf16; s-PAIR blocks for full
// 128-B line utilization on the read side (single-s blocks waste half of every line
// because the adjacent s-segment is fetched by a different block on another XCD).
__global__ __launch_bounds__(256) void transpose_x(const float* x, float* xt, u16* xtbf) {
    int bx = blockIdx.x;
    int nn = bx >> 5, sp = bx & 31;
    int s0 = sp * 2;
    __shared__ float tile[2][16][257];
    int t = threadIdx.x;
    const float* xb = x + (size_t)nn * 262144 + (size_t)s0 * 16;
#pragma unroll
    for (int chunk = 0; chunk < 32; chunk++) {
        int e = chunk * 256 + t;
        int c = e >> 5;
        int idx = e & 31;              // = so*16 + pp -> 32 consecutive floats = 128 B
        int so = idx >> 4, pp = idx & 15;
        tile[so][pp][c] = xb[(size_t)c * 1024 + idx];
    }
    __syncthreads();
#pragma unroll
    for (int so = 0; so < 2; so++)
#pragma unroll
        for (int pp = 0; pp < 16; pp++) {
            float v = tile[so][pp][t];
            size_t o = ((size_t)(nn * 16 + pp) * 64 + s0 + so) * 256 + t;
            xt[o] = v;
            xtbf[o] = f2bf(v);
        }
}

// ---------------- instance norm + cosine sim + argmax (float64, LDS-staged) ----------------
__global__ __launch_bounds__(256) void norm_sim(const float* xt, const float* prot, int* hard) {
    int b = blockIdx.x;
    int pp = b & 15, nn = b >> 4;
    __shared__ float xs[64][257];
    __shared__ double wk[4][256];
    __shared__ double smu[256];
    __shared__ double srstd[256];
    __shared__ double offk[4];
    __shared__ double dd[64][5];
    int t = threadIdx.x, w = t >> 6, lane = t & 63;

    const float* xb = xt + (size_t)b * 64 * 256 + t;
    double s1 = 0.0, s2 = 0.0;
#pragma unroll 8
    for (int s = 0; s < 64; s++) {
        float v = xb[(size_t)s * 256];
        xs[s][t] = v;
        double dv = (double)v;
        s1 += dv; s2 += dv * dv;
    }
    double mu = s1 * (1.0 / 64.0);
    double var = s2 * (1.0 / 64.0) - mu * mu;
    smu[t] = mu;
    srstd[t] = 1.0 / sqrt(var + 1e-5);
    __syncthreads();

    {
        double pv[4]; double ss = 0.0;
#pragma unroll
        for (int j = 0; j < 4; j++) {
            pv[j] = (double)prot[((size_t)pp * 4 + w) * 256 + lane + 64 * j];
            ss += pv[j] * pv[j];
        }
        ss = wave_sum_d(ss);
        double rn = 1.0 / sqrt(ss);
        double po = 0.0;
#pragma unroll
        for (int j = 0; j < 4; j++) {
            int c = lane + 64 * j;
            double wv = pv[j] * rn * srstd[c];
            wk[w][c] = wv;
            po += wv * smu[c];
        }
        po = wave_sum_d(po);
        if (lane == 0) offk[w] = po;
    }
    __syncthreads();

    {
        int s = lane;
        const float* xr = &xs[s][0];
        const double* wr = &wk[w][0];
        double a0 = 0.0, a1 = 0.0, a2 = 0.0, a3 = 0.0;
#pragma unroll 8
        for (int c = 0; c < 256; c += 4) {
            a0 = fma((double)xr[c],     wr[c],     a0);
            a1 = fma((double)xr[c + 1], wr[c + 1], a1);
            a2 = fma((double)xr[c + 2], wr[c + 2], a2);
            a3 = fma((double)xr[c + 3], wr[c + 3], a3);
        }
        dd[s][w] = ((a0 + a1) + (a2 + a3)) - offk[w];
    }
    __syncthreads();

    if (t < 64) {
        double d0 = dd[t][0], d1 = dd[t][1], d2 = dd[t][2], d3 = dd[t][3];
        int best = 0; double bv = d0;
        if (d1 > bv) { bv = d1; best = 1; }
        if (d2 > bv) { bv = d2; best = 2; }
        if (d3 > bv) { best = 3; }
        hard[((pp * 64 + nn) << 6) + t] = best;
    }
}

// ---------------- mode over parts -> cluster_indices (fp32 out) ----------------
__global__ __launch_bounds__(256) void cluster_mode(const int* hard, float* outp) {
    int tid = blockIdx.x * 256 + threadIdx.x;
    int nn = tid >> 6, s = tid & 63;
    int cnt[4] = {0, 0, 0, 0};
#pragma unroll
    for (int p = 0; p < 16; p++) cnt[hard[((p * 64 + nn) << 6) + s]]++;
    int best = 0;
#pragma unroll
    for (int k = 1; k < 4; k++) if (cnt[k] > cnt[best]) best = k;
    outp[tid] = (float)best;
}

// ======== MEGA-FUSED: QKV gemm + causal attention + Wo gemm + residual + scatter-max ========
// One block per batch b, wave w = head w. xs LDS-staged (round-5 proven). Occupancy is
// LDS-capped at 2 blocks/CU -> VGPR budget up to 256 is FREE: spent on Q+K interleaved
// accumulators and V-gemm/softmax overlap. Epilogue scratch-free (ballot + packed nibbles).
// (Round-7 verified config: 104.5 us. 8-wave M-split variants regress: barrier serialization.)
__global__ __launch_bounds__(256, 2) void fused_attn(const u16* xtbf, const u16* Wt,
                                                  const float* bq, const float* bk, const float* bv,
                                                  const float* bo, const int* hard, u16* clus) {
    __shared__ u16 xs[64][264];     // x2[b] bf16; stride 264 u16 = 132 dw -> conflict-free b128
    __shared__ u16 scr[4][64][72];  // per-wave scratch; stride 72 u16 = 36 dw -> conflict-free
    __shared__ int sidx[64];
    int t = threadIdx.x;
    int w = t >> 6, lane = t & 63;
    int l15 = lane & 15, qd = lane >> 4;
    int b = blockIdx.x;
    int pp = b & 15, nn = b >> 4;

    // stage x tile + cluster indices
    {
        const u16* xb = xtbf + (size_t)b * 16384;
#pragma unroll
        for (int i = 0; i < 8; i++) {
            int e = i * 256 + t;
            int r = e >> 5, g = e & 31;
            *(uint4*)&xs[r][g * 8] = *(const uint4*)(xb + (size_t)r * 256 + g * 8);
        }
        if (t < 64) sidx[t] = hard[((pp * 64 + nn) << 6) + t];
    }
    __syncthreads();

    const f32x4 zero4 = {0.f, 0.f, 0.f, 0.f};
    u16* sw = &scr[w][0][0];

    // ---- Q and K gemms interleaved: shared A-frags, separate accumulators ----
    f32x4 accQ[4][4], accK[4][4];
#pragma unroll
    for (int mt = 0; mt < 4; mt++)
#pragma unroll
        for (int nt = 0; nt < 4; nt++) { accQ[mt][nt] = zero4; accK[mt][nt] = zero4; }
    {
        const u16* WQ = Wt + (size_t)(w * 64) * 256;
        const u16* WK = WQ + 65536;
#pragma unroll
        for (int kc = 0; kc < 8; kc++) {
            bf16x8 af[4], bq4[4], bk4[4];
#pragma unroll
            for (int mt = 0; mt < 4; mt++)
                af[mt] = *(const bf16x8*)(&xs[mt * 16 + l15][kc * 32 + qd * 8]);
#pragma unroll
            for (int nt = 0; nt < 4; nt++) {
                bq4[nt] = *(const bf16x8*)(WQ + (size_t)(nt * 16 + l15) * 256 + kc * 32 + qd * 8);
                bk4[nt] = *(const bf16x8*)(WK + (size_t)(nt * 16 + l15) * 256 + kc * 32 + qd * 8);
            }
#pragma unroll
            for (int mt = 0; mt < 4; mt++)
#pragma unroll
                for (int nt = 0; nt < 4; nt++) {
                    accQ[mt][nt] = __builtin_amdgcn_mfma_f32_16x16x32_bf16(af[mt], bq4[nt], accQ[mt][nt], 0, 0, 0);
                    accK[mt][nt] = __builtin_amdgcn_mfma_f32_16x16x32_bf16(af[mt], bk4[nt], accK[mt][nt], 0, 0, 0);
                }
        }
    }

    // ---- repack Q -> scr -> qf ----
    bf16x8 qf[2][4], kf[2][4];
#pragma unroll
    for (int mt = 0; mt < 4; mt++)
#pragma unroll
        for (int nt = 0; nt < 4; nt++) {
            int col = nt * 16 + l15;
            float bb = bq[w * 64 + col];
#pragma unroll
            for (int r = 0; r < 4; r++)
                sw[(mt * 16 + qd * 4 + r) * 72 + col] = f2bf(accQ[mt][nt][r] + bb);
        }
#pragma unroll
    for (int kc2 = 0; kc2 < 2; kc2++)
#pragma unroll
        for (int mt = 0; mt < 4; mt++)
            qf[kc2][mt] = *(const bf16x8*)(sw + (mt * 16 + l15) * 72 + kc2 * 32 + qd * 8);

    // ---- repack K -> scr -> kf ----
#pragma unroll
    for (int mt = 0; mt < 4; mt++)
#pragma unroll
        for (int nt = 0; nt < 4; nt++) {
            int col = nt * 16 + l15;
            float bb = bk[w * 64 + col];
#pragma unroll
            for (int r = 0; r < 4; r++)
                sw[(mt * 16 + qd * 4 + r) * 72 + col] = f2bf(accK[mt][nt][r] + bb);
        }
#pragma unroll
    for (int kc2 = 0; kc2 < 2; kc2++)
#pragma unroll
        for (int mt = 0; mt < 4; mt++)
            kf[kc2][mt] = *(const bf16x8*)(sw + (mt * 16 + l15) * 72 + kc2 * 32 + qd * 8);

    // ---- S = Q K^T ----
    f32x4 accS[4][4];
#pragma unroll
    for (int mt = 0; mt < 4; mt++)
#pragma unroll
        for (int nt = 0; nt < 4; nt++) accS[mt][nt] = zero4;
#pragma unroll
    for (int kc2 = 0; kc2 < 2; kc2++)
#pragma unroll
        for (int mt = 0; mt < 4; mt++)
#pragma unroll
            for (int nt = 0; nt < 4; nt++)
                accS[mt][nt] = __builtin_amdgcn_mfma_f32_16x16x32_bf16(qf[kc2][mt], kf[kc2][nt], accS[mt][nt], 0, 0, 0);

    // ---- V gemm (independent of S; overlaps the softmax VALU chain below) ----
    f32x4 accV[4][4];
#pragma unroll
    for (int mt = 0; mt < 4; mt++)
#pragma unroll
        for (int nt = 0; nt < 4; nt++) accV[mt][nt] = zero4;
    {
        const u16* WV = Wt + 2 * 65536 + (size_t)(w * 64) * 256;
#pragma unroll
        for (int kc = 0; kc < 8; kc++) {
            bf16x8 af[4], bv4[4];
#pragma unroll
            for (int mt = 0; mt < 4; mt++)
                af[mt] = *(const bf16x8*)(&xs[mt * 16 + l15][kc * 32 + qd * 8]);
#pragma unroll
            for (int nt = 0; nt < 4; nt++)
                bv4[nt] = *(const bf16x8*)(WV + (size_t)(nt * 16 + l15) * 256 + kc * 32 + qd * 8);
#pragma unroll
            for (int mt = 0; mt < 4; mt++)
#pragma unroll
                for (int nt = 0; nt < 4; nt++)
                    accV[mt][nt] = __builtin_amdgcn_mfma_f32_16x16x32_bf16(af[mt], bv4[nt], accV[mt][nt], 0, 0, 0);
        }
    }

    // ---- causal mask + softmax on accS -> P (bf16) into scratch ----
#pragma unroll
    for (int mt = 0; mt < 4; mt++) {
#pragma unroll
        for (int r = 0; r < 4; r++) {
            int row = mt * 16 + qd * 4 + r;
            float v[4];
#pragma unroll
            for (int nt = 0; nt < 4; nt++) {
                int col = nt * 16 + l15;
                float sv = accS[mt][nt][r] * 0.125f;
                if (col > row) sv = FMIN32;
                v[nt] = sv;
            }
            float m = fmaxf(fmaxf(v[0], v[1]), fmaxf(v[2], v[3]));
#pragma unroll
            for (int msk = 1; msk < 16; msk <<= 1) m = fmaxf(m, __shfl_xor(m, msk, 64));
            float e[4], ssum = 0.f;
#pragma unroll
            for (int nt = 0; nt < 4; nt++) { e[nt] = expf(v[nt] - m); ssum += e[nt]; }
#pragma unroll
            for (int msk = 1; msk < 16; msk <<= 1) ssum += __shfl_xor(ssum, msk, 64);
            float rinv = 1.0f / ssum;
#pragma unroll
            for (int nt = 0; nt < 4; nt++) sw[row * 72 + nt * 16 + l15] = f2bf(e[nt] * rinv);
        }
    }
    bf16x8 pf[2][4];
#pragma unroll
    for (int kc2 = 0; kc2 < 2; kc2++)
#pragma unroll
        for (int mt = 0; mt < 4; mt++)
            pf[kc2][mt] = *(const bf16x8*)(sw + (mt * 16 + l15) * 72 + kc2 * 32 + qd * 8);

    // ---- V^T repack (accV + bias) -> scr [d][s] -> vf ----
#pragma unroll
    for (int mt = 0; mt < 4; mt++)
#pragma unroll
        for (int nt = 0; nt < 4; nt++) {
            int d = nt * 16 + l15;
            float bb = bv[w * 64 + d];
            ushort4 pk;
            pk.x = f2bf(accV[mt][nt][0] + bb);
            pk.y = f2bf(accV[mt][nt][1] + bb);
            pk.z = f2bf(accV[mt][nt][2] + bb);
            pk.w = f2bf(accV[mt][nt][3] + bb);
            *(ushort4*)(sw + d * 72 + mt * 16 + qd * 4) = pk;
        }
    bf16x8 vf[2][4];
#pragma unroll
    for (int kc2 = 0; kc2 < 2; kc2++)
#pragma unroll
        for (int nt = 0; nt < 4; nt++)
            vf[kc2][nt] = *(const bf16x8*)(sw + (nt * 16 + l15) * 72 + kc2 * 32 + qd * 8);

    // ---- O = P @ V ----
    f32x4 acc[4][4];
#pragma unroll
    for (int mt = 0; mt < 4; mt++)
#pragma unroll
        for (int nt = 0; nt < 4; nt++) acc[mt][nt] = zero4;
#pragma unroll
    for (int kc2 = 0; kc2 < 2; kc2++)
#pragma unroll
        for (int nt = 0; nt < 4; nt++)
#pragma unroll
            for (int mt = 0; mt < 4; mt++)
                acc[mt][nt] = __builtin_amdgcn_mfma_f32_16x16x32_bf16(pf[kc2][mt], vf[kc2][nt], acc[mt][nt], 0, 0, 0);

    // ---- O head -> scratch [q][d] bf16 ----
#pragma unroll
    for (int mt = 0; mt < 4; mt++)
#pragma unroll
        for (int nt = 0; nt < 4; nt++)
#pragma unroll
            for (int r = 0; r < 4; r++)
                sw[(mt * 16 + qd * 4 + r) * 72 + nt * 16 + l15] = f2bf(acc[mt][nt][r]);
    __syncthreads();

    // ---- Wo gemm: out cols w*64..; A = O concat (from 4 scratches), B = Wo rows ----
    {
        const u16* WO = Wt + 3 * 65536 + (size_t)(w * 64) * 256;
#pragma unroll
        for (int mt = 0; mt < 4; mt++)
#pragma unroll
            for (int nt = 0; nt < 4; nt++) acc[mt][nt] = zero4;
#pragma unroll
        for (int kc = 0; kc < 8; kc++) {
            int h = kc >> 1, k2 = kc & 1;
            bf16x8 af[4], bfr[4];
#pragma unroll
            for (int mt = 0; mt < 4; mt++)
                af[mt] = *(const bf16x8*)(&scr[h][mt * 16 + l15][k2 * 32 + qd * 8]);
#pragma unroll
            for (int nt = 0; nt < 4; nt++)
                bfr[nt] = *(const bf16x8*)(WO + (size_t)(nt * 16 + l15) * 256 + kc * 32 + qd * 8);
#pragma unroll
            for (int mt = 0; mt < 4; mt++)
#pragma unroll
                for (int nt = 0; nt < 4; nt++)
                    acc[mt][nt] = __builtin_amdgcn_mfma_f32_16x16x32_bf16(af[mt], bfr[nt], acc[mt][nt], 0, 0, 0);
        }
    }

    // ---- epilogue: +bias +residual (xs LDS), scratch-free grouped max, write clus ----
#pragma unroll
    for (int mt = 0; mt < 4; mt++)
#pragma unroll
        for (int nt = 0; nt < 4; nt++) {
            int col = w * 64 + nt * 16 + l15;
            float bb = bo[col];
#pragma unroll
            for (int r = 0; r < 4; r++) {
                int s = mt * 16 + qd * 4 + r;
                acc[mt][nt][r] += bb + bf2f(xs[s][col]);
            }
        }
    int myidx = sidx[lane];
    // pack this lane's 16 row-cluster-ids into 2 u32 nibble arrays (no reg array)
    u32 sr0 = 0, sr1 = 0;
#pragma unroll
    for (int mt = 0; mt < 4; mt++)
#pragma unroll
        for (int r = 0; r < 4; r++) {
            int idx = mt * 4 + r;
            u32 v = (u32)sidx[mt * 16 + qd * 4 + r];
            if (idx < 8) sr0 |= v << (idx * 4); else sr1 |= v << ((idx - 8) * 4);
        }
    size_t ob = ((size_t)(pp * 64 + nn)) * 1024;
#pragma unroll
    for (int k = 0; k < 4; k++) {
        unsigned long long bal = __ballot(myidx == k);
        int ck = __popcll(bal);
        float m0 = FMIN32, m1 = FMIN32, m2 = FMIN32, m3 = FMIN32;
#pragma unroll
        for (int mt = 0; mt < 4; mt++)
#pragma unroll
            for (int r = 0; r < 4; r++) {
                int idx = mt * 4 + r;
                u32 kk = ((idx < 8 ? sr0 : sr1) >> ((idx & 7) * 4)) & 15u;
                bool tk = (kk == (u32)k);
                m0 = tk ? fmaxf(m0, acc[mt][0][r]) : m0;
                m1 = tk ? fmaxf(m1, acc[mt][1][r]) : m1;
                m2 = tk ? fmaxf(m2, acc[mt][2][r]) : m2;
                m3 = tk ? fmaxf(m3, acc[mt][3][r]) : m3;
            }
        float mm[4] = {m0, m1, m2, m3};
#pragma unroll
        for (int nt = 0; nt < 4; nt++) {
            float m = mm[nt];
            m = fmaxf(m, __shfl_xor(m, 16, 64));
            m = fmaxf(m, __shfl_xor(m, 32, 64));
            if (ck < 64) m = fmaxf(m, 0.0f);
            if (qd == 0) clus[ob + k * 256 + w * 64 + nt * 16 + l15] = f2bf(m);
        }
    }
}

// ---- MFMA SeparateFCs, K-split: partial[kz][n][o][p] over kz chunks of 256 ----
__global__ __launch_bounds__(256) void gemm_fc_mfma(const u16* clus, const u16* fcT, float* part) {
    int p = blockIdx.x, by = blockIdx.y, kz = blockIdx.z;
    __shared__ u16 As[64 * 32];
    __shared__ u16 Bs[64 * 32];
    const u16* Ap = clus + (size_t)p * 65536 + kz * 256;
    const u16* Bp = fcT + (size_t)p * 262144 + (size_t)(by * 64) * 1024 + kz * 256;
    int t = threadIdx.x;
    int w = t >> 6, lane = t & 63;
    int l15 = lane & 15, qd = lane >> 4;
    f32x4 acc[4] = {};
    int srow = t >> 2, scg = t & 3;
    for (int kc = 0; kc < 256; kc += 32) {
        *(uint4*)(As + srow * 32 + scg * 8) =
            *(const uint4*)(Ap + (size_t)srow * 1024 + kc + scg * 8);
        *(uint4*)(Bs + srow * 32 + scg * 8) =
            *(const uint4*)(Bp + (size_t)srow * 1024 + kc + scg * 8);
        __syncthreads();
        bf16x8 bfr = *(const bf16x8*)(Bs + (w * 16 + l15) * 32 + qd * 8);
#pragma unroll
        for (int mt = 0; mt < 4; mt++) {
            bf16x8 af = *(const bf16x8*)(As + (mt * 16 + l15) * 32 + qd * 8);
            acc[mt] = __builtin_amdgcn_mfma_f32_16x16x32_bf16(af, bfr, acc[mt], 0, 0, 0);
        }
        __syncthreads();
    }
#pragma unroll
    for (int mt = 0; mt < 4; mt++)
#pragma unroll
        for (int r = 0; r < 4; r++) {
            int n = mt * 16 + qd * 4 + r;
            int o = by * 64 + w * 16 + l15;
            part[(size_t)kz * 262144 + (size_t)n * 4096 + (size_t)o * 16 + p] = acc[mt][r];
        }
}

// ---- sum 4 K-partials -> out_fc (float4 vectorized) ----
__global__ __launch_bounds__(256) void reduce_fc(const float* part, float* out) {
    int tid = blockIdx.x * 256 + threadIdx.x;
    const float4* p0 = (const float4*)part;
    float4 a = p0[tid];
    float4 b = p0[65536 + tid];
    float4 c = p0[131072 + tid];
    float4 d = p0[196608 + tid];
    float4 r;
    r.x = a.x + b.x + c.x + d.x;
    r.y = a.y + b.y + c.y + d.y;
    r.z = a.z + b.z + c.z + d.z;
    r.w = a.w + b.w + c.w + d.w;
    ((float4*)out)[tid] = r;
}

extern "C" void kernel_launch(void* const* d_in, const int* in_sizes, int n_in,
                              void* d_out, int out_size, void* d_ws, size_t ws_size,
                              hipStream_t stream) {
    const float* x    = (const float*)d_in[0];
    const float* prot = (const float*)d_in[1];
    const float* Wq   = (const float*)d_in[2];
    const float* bq   = (const float*)d_in[3];
    const float* Wk   = (const float*)d_in[4];
    const float* bk   = (const float*)d_in[5];
    const float* Wv   = (const float*)d_in[6];
    const float* bv   = (const float*)d_in[7];
    const float* Wo   = (const float*)d_in[8];
    const float* bo   = (const float*)d_in[9];
    const float* fcb  = (const float*)d_in[10];

    // Workspace map:
    //   [0,      33.5M)  xtbf bf16
    //   [33.5M, 100.7M)  xt fp32 (dead after norm_sim) -> fcpart (4 MB) reuses this
    //   [134.2M,+0.5M )  Wt bf16
    //   [134.7M,+8.4M )  fcT bf16
    //   [143.1M,+0.26M)  hard int32
    //   [143.4M,+2.1M )  clus bf16
    char* ws = (char*)d_ws;
    u16*   xtbf = (u16*)(ws + 0);
    float* xt   = (float*)(ws + 33554432);
    float* fcpart = (float*)(ws + 33554432);
    u16*   Wt   = (u16*)(ws + 134217728);
    u16*   fcT  = (u16*)(ws + 134742016);
    int*   hard = (int*)(ws + 143130624);
    u16*   clus = (u16*)(ws + 143392768);

    float* out_fc = (float*)d_out;
    float* out_ci = (float*)d_out + 262144;

    dim3 B(256);
    convert_w<<<dim3(8, 8, 4), B, 0, stream>>>(Wq, Wk, Wv, Wo, Wt);
    convert_fc<<<dim3(32, 8, 16), B, 0, stream>>>(fcb, fcT);
    transpose_x<<<dim3(2048), B, 0, stream>>>(x, xt, xtbf);
    norm_sim<<<dim3(1024), B, 0, stream>>>(xt, prot, hard);
    cluster_mode<<<dim3(16), B, 0, stream>>>(hard, out_ci);
    fused_attn<<<dim3(1024), B, 0, stream>>>(xtbf, Wt, bq, bk, bv, bo, hard, clus);
    gemm_fc_mfma<<<dim3(16, 4, 4), B, 0, stream>>>(clus, fcT, fcpart);
    reduce_fc<<<dim3(256), B, 0, stream>>>(fcpart, out_fc);
}

// Round 11
// 268.931 us; speedup vs baseline: 1.3123x; 1.0490x over previous
//
#include <hip/hip_runtime.h>

typedef unsigned short u16;
typedef unsigned int u32;
typedef __attribute__((ext_vector_type(8))) short bf16x8;
typedef __attribute__((ext_vector_type(4))) float f32x4;

typedef __attribute__((address_space(1))) const unsigned int gu32;
typedef __attribute__((address_space(3))) unsigned int lu32;

#define FMIN32 -3.402823466e38f

__device__ inline u16 f2bf(float f) {
    u32 x = __float_as_uint(f);
    u32 r = x + 0x7FFFu + ((x >> 16) & 1u);
    return (u16)(r >> 16);
}
__device__ inline float bf2f(u16 u) { return __uint_as_float(((u32)u) << 16); }

__device__ inline double wave_sum_d(double v) {
#pragma unroll
    for (int m = 1; m < 64; m <<= 1) v += __shfl_xor(v, m, 64);
    return v;
}

// ======== PREP (merged): transpose_x (blk 0..2047) | convert_w (2048..2303) |
//                         convert_fc (2304..6399) — independent, one launch ========
__global__ __launch_bounds__(256) void prep(const float* x, float* xt, u16* xtbf,
                                            const float* W0, const float* W1,
                                            const float* W2, const float* W3, u16* Wt,
                                            const float* F, u16* Ofc) {
    __shared__ float tile[2][16][257];   // 32.9 KB (union: converts use a corner)
    int blk = blockIdx.x;
    int t = threadIdx.x;
    if (blk < 2048) {
        // ---- transpose_x: s-pair blocks for full 128-B line utilization ----
        int nn = blk >> 5, sp = blk & 31;
        int s0 = sp * 2;
        const float* xb = x + (size_t)nn * 262144 + (size_t)s0 * 16;
#pragma unroll
        for (int chunk = 0; chunk < 32; chunk++) {
            int e = chunk * 256 + t;
            int c = e >> 5;
            int idx = e & 31;              // so*16+pp -> 32 consecutive floats = 128 B
            int so = idx >> 4, pp = idx & 15;
            tile[so][pp][c] = xb[(size_t)c * 1024 + idx];
        }
        __syncthreads();
#pragma unroll
        for (int so = 0; so < 2; so++)
#pragma unroll
            for (int pp = 0; pp < 16; pp++) {
                float v = tile[so][pp][t];
                size_t o = ((size_t)(nn * 16 + pp) * 64 + s0 + so) * 256 + t;
                xt[o] = v;
                xtbf[o] = f2bf(v);
            }
    } else if (blk < 2304) {
        // ---- convert_w: W[k][n] fp32 -> Wt[n][k] bf16 ----
        int i = blk - 2048;
        int bx = i & 7, by = (i >> 3) & 7, z = i >> 6;
        const float* Ws[4] = {W0, W1, W2, W3};
        const float* W = Ws[z];
        u16* O = Wt + (size_t)z * 65536;
        float (*tl)[257] = tile[0];   // use 32x33 corner of union (stride 257 safe)
#pragma unroll
        for (int i2 = 0; i2 < 4; i2++) {
            int e = i2 * 256 + t; int tr = e >> 5, tc = e & 31;
            tl[tr][tc] = W[(size_t)(bx * 32 + tr) * 256 + by * 32 + tc];
        }
        __syncthreads();
#pragma unroll
        for (int i2 = 0; i2 < 4; i2++) {
            int e = i2 * 256 + t; int tr = e >> 5, tc = e & 31;
            O[(size_t)(by * 32 + tr) * 256 + bx * 32 + tc] = f2bf(tl[tc][tr]);
        }
    } else {
        // ---- convert_fc: fc_bin[p][c'][o] fp32 -> fcT[p][o][c'] bf16 ----
        int i = blk - 2304;
        int bx = i & 31, by = (i >> 5) & 7, p = i >> 8;
        const float* Fp = F + (size_t)p * 1024 * 256;
        u16* Op = Ofc + (size_t)p * 256 * 1024;
        float (*tl)[257] = tile[0];
#pragma unroll
        for (int i2 = 0; i2 < 4; i2++) {
            int e = i2 * 256 + t; int tr = e >> 5, tc = e & 31;
            tl[tr][tc] = Fp[(size_t)(bx * 32 + tr) * 256 + by * 32 + tc];
        }
        __syncthreads();
#pragma unroll
        for (int i2 = 0; i2 < 4; i2++) {
            int e = i2 * 256 + t; int tr = e >> 5, tc = e & 31;
            Op[(size_t)(by * 32 + tr) * 1024 + bx * 32 + tc] = f2bf(tl[tc][tr]);
        }
    }
}

// ---------------- instance norm + cosine sim + argmax (float64, LDS-staged) ----------------
__global__ __launch_bounds__(256) void norm_sim(const float* xt, const float* prot, int* hard) {
    int b = blockIdx.x;
    int pp = b & 15, nn = b >> 4;
    __shared__ float xs[64][257];
    __shared__ double wk[4][256];
    __shared__ double smu[256];
    __shared__ double srstd[256];
    __shared__ double offk[4];
    __shared__ double dd[64][5];
    int t = threadIdx.x, w = t >> 6, lane = t & 63;

    const float* xb = xt + (size_t)b * 64 * 256 + t;
    double s1 = 0.0, s2 = 0.0;
#pragma unroll 8
    for (int s = 0; s < 64; s++) {
        float v = xb[(size_t)s * 256];
        xs[s][t] = v;
        double dv = (double)v;
        s1 += dv; s2 += dv * dv;
    }
    double mu = s1 * (1.0 / 64.0);
    double var = s2 * (1.0 / 64.0) - mu * mu;
    smu[t] = mu;
    srstd[t] = 1.0 / sqrt(var + 1e-5);
    __syncthreads();

    {
        double pv[4]; double ss = 0.0;
#pragma unroll
        for (int j = 0; j < 4; j++) {
            pv[j] = (double)prot[((size_t)pp * 4 + w) * 256 + lane + 64 * j];
            ss += pv[j] * pv[j];
        }
        ss = wave_sum_d(ss);
        double rn = 1.0 / sqrt(ss);
        double po = 0.0;
#pragma unroll
        for (int j = 0; j < 4; j++) {
            int c = lane + 64 * j;
            double wv = pv[j] * rn * srstd[c];
            wk[w][c] = wv;
            po += wv * smu[c];
        }
        po = wave_sum_d(po);
        if (lane == 0) offk[w] = po;
    }
    __syncthreads();

    {
        int s = lane;
        const float* xr = &xs[s][0];
        const double* wr = &wk[w][0];
        double a0 = 0.0, a1 = 0.0, a2 = 0.0, a3 = 0.0;
#pragma unroll 8
        for (int c = 0; c < 256; c += 4) {
            a0 = fma((double)xr[c],     wr[c],     a0);
            a1 = fma((double)xr[c + 1], wr[c + 1], a1);
            a2 = fma((double)xr[c + 2], wr[c + 2], a2);
            a3 = fma((double)xr[c + 3], wr[c + 3], a3);
        }
        dd[s][w] = ((a0 + a1) + (a2 + a3)) - offk[w];
    }
    __syncthreads();

    if (t < 64) {
        double d0 = dd[t][0], d1 = dd[t][1], d2 = dd[t][2], d3 = dd[t][3];
        int best = 0; double bv = d0;
        if (d1 > bv) { bv = d1; best = 1; }
        if (d2 > bv) { bv = d2; best = 2; }
        if (d3 > bv) { best = 3; }
        hard[((pp * 64 + nn) << 6) + t] = best;
    }
}

// ======== MEGA-FUSED: QKV gemm + causal attention + Wo gemm + residual + scatter-max ========
// FROZEN at the round-7/round-10 measured config (104 us): one block per batch, wave = head,
// xs LDS-staged, Q+K interleaved, V-gemm overlapped with softmax, scratch-free epilogue.
__global__ __launch_bounds__(256, 2) void fused_attn(const u16* xtbf, const u16* Wt,
                                                  const float* bq, const float* bk, const float* bv,
                                                  const float* bo, const int* hard, u16* clus) {
    __shared__ u16 xs[64][264];     // x2[b] bf16; stride 264 u16 = 132 dw -> conflict-free b128
    __shared__ u16 scr[4][64][72];  // per-wave scratch; stride 72 u16 = 36 dw -> conflict-free
    __shared__ int sidx[64];
    int t = threadIdx.x;
    int w = t >> 6, lane = t & 63;
    int l15 = lane & 15, qd = lane >> 4;
    int b = blockIdx.x;
    int pp = b & 15, nn = b >> 4;

    // stage x tile + cluster indices
    {
        const u16* xb = xtbf + (size_t)b * 16384;
#pragma unroll
        for (int i = 0; i < 8; i++) {
            int e = i * 256 + t;
            int r = e >> 5, g = e & 31;
            *(uint4*)&xs[r][g * 8] = *(const uint4*)(xb + (size_t)r * 256 + g * 8);
        }
        if (t < 64) sidx[t] = hard[((pp * 64 + nn) << 6) + t];
    }
    __syncthreads();

    const f32x4 zero4 = {0.f, 0.f, 0.f, 0.f};
    u16* sw = &scr[w][0][0];

    // ---- Q and K gemms interleaved: shared A-frags, separate accumulators ----
    f32x4 accQ[4][4], accK[4][4];
#pragma unroll
    for (int mt = 0; mt < 4; mt++)
#pragma unroll
        for (int nt = 0; nt < 4; nt++) { accQ[mt][nt] = zero4; accK[mt][nt] = zero4; }
    {
        const u16* WQ = Wt + (size_t)(w * 64) * 256;
        const u16* WK = WQ + 65536;
#pragma unroll
        for (int kc = 0; kc < 8; kc++) {
            bf16x8 af[4], bq4[4], bk4[4];
#pragma unroll
            for (int mt = 0; mt < 4; mt++)
                af[mt] = *(const bf16x8*)(&xs[mt * 16 + l15][kc * 32 + qd * 8]);
#pragma unroll
            for (int nt = 0; nt < 4; nt++) {
                bq4[nt] = *(const bf16x8*)(WQ + (size_t)(nt * 16 + l15) * 256 + kc * 32 + qd * 8);
                bk4[nt] = *(const bf16x8*)(WK + (size_t)(nt * 16 + l15) * 256 + kc * 32 + qd * 8);
            }
#pragma unroll
            for (int mt = 0; mt < 4; mt++)
#pragma unroll
                for (int nt = 0; nt < 4; nt++) {
                    accQ[mt][nt] = __builtin_amdgcn_mfma_f32_16x16x32_bf16(af[mt], bq4[nt], accQ[mt][nt], 0, 0, 0);
                    accK[mt][nt] = __builtin_amdgcn_mfma_f32_16x16x32_bf16(af[mt], bk4[nt], accK[mt][nt], 0, 0, 0);
                }
        }
    }

    // ---- repack Q -> scr -> qf ----
    bf16x8 qf[2][4], kf[2][4];
#pragma unroll
    for (int mt = 0; mt < 4; mt++)
#pragma unroll
        for (int nt = 0; nt < 4; nt++) {
            int col = nt * 16 + l15;
            float bb = bq[w * 64 + col];
#pragma unroll
            for (int r = 0; r < 4; r++)
                sw[(mt * 16 + qd * 4 + r) * 72 + col] = f2bf(accQ[mt][nt][r] + bb);
        }
#pragma unroll
    for (int kc2 = 0; kc2 < 2; kc2++)
#pragma unroll
        for (int mt = 0; mt < 4; mt++)
            qf[kc2][mt] = *(const bf16x8*)(sw + (mt * 16 + l15) * 72 + kc2 * 32 + qd * 8);

    // ---- repack K -> scr -> kf ----
#pragma unroll
    for (int mt = 0; mt < 4; mt++)
#pragma unroll
        for (int nt = 0; nt < 4; nt++) {
            int col = nt * 16 + l15;
            float bb = bk[w * 64 + col];
#pragma unroll
            for (int r = 0; r < 4; r++)
                sw[(mt * 16 + qd * 4 + r) * 72 + col] = f2bf(accK[mt][nt][r] + bb);
        }
#pragma unroll
    for (int kc2 = 0; kc2 < 2; kc2++)
#pragma unroll
        for (int mt = 0; mt < 4; mt++)
            kf[kc2][mt] = *(const bf16x8*)(sw + (mt * 16 + l15) * 72 + kc2 * 32 + qd * 8);

    // ---- S = Q K^T ----
    f32x4 accS[4][4];
#pragma unroll
    for (int mt = 0; mt < 4; mt++)
#pragma unroll
        for (int nt = 0; nt < 4; nt++) accS[mt][nt] = zero4;
#pragma unroll
    for (int kc2 = 0; kc2 < 2; kc2++)
#pragma unroll
        for (int mt = 0; mt < 4; mt++)
#pragma unroll
            for (int nt = 0; nt < 4; nt++)
                accS[mt][nt] = __builtin_amdgcn_mfma_f32_16x16x32_bf16(qf[kc2][mt], kf[kc2][nt], accS[mt][nt], 0, 0, 0);

    // ---- V gemm (independent of S; overlaps the softmax VALU chain below) ----
    f32x4 accV[4][4];
#pragma unroll
    for (int mt = 0; mt < 4; mt++)
#pragma unroll
        for (int nt = 0; nt < 4; nt++) accV[mt][nt] = zero4;
    {
        const u16* WV = Wt + 2 * 65536 + (size_t)(w * 64) * 256;
#pragma unroll
        for (int kc = 0; kc < 8; kc++) {
            bf16x8 af[4], bv4[4];
#pragma unroll
            for (int mt = 0; mt < 4; mt++)
                af[mt] = *(const bf16x8*)(&xs[mt * 16 + l15][kc * 32 + qd * 8]);
#pragma unroll
            for (int nt = 0; nt < 4; nt++)
                bv4[nt] = *(const bf16x8*)(WV + (size_t)(nt * 16 + l15) * 256 + kc * 32 + qd * 8);
#pragma unroll
            for (int mt = 0; mt < 4; mt++)
#pragma unroll
                for (int nt = 0; nt < 4; nt++)
                    accV[mt][nt] = __builtin_amdgcn_mfma_f32_16x16x32_bf16(af[mt], bv4[nt], accV[mt][nt], 0, 0, 0);
        }
    }

    // ---- causal mask + softmax on accS -> P (bf16) into scratch ----
#pragma unroll
    for (int mt = 0; mt < 4; mt++) {
#pragma unroll
        for (int r = 0; r < 4; r++) {
            int row = mt * 16 + qd * 4 + r;
            float v[4];
#pragma unroll
            for (int nt = 0; nt < 4; nt++) {
                int col = nt * 16 + l15;
                float sv = accS[mt][nt][r] * 0.125f;
                if (col > row) sv = FMIN32;
                v[nt] = sv;
            }
            float m = fmaxf(fmaxf(v[0], v[1]), fmaxf(v[2], v[3]));
#pragma unroll
            for (int msk = 1; msk < 16; msk <<= 1) m = fmaxf(m, __shfl_xor(m, msk, 64));
            float e[4], ssum = 0.f;
#pragma unroll
            for (int nt = 0; nt < 4; nt++) { e[nt] = expf(v[nt] - m); ssum += e[nt]; }
#pragma unroll
            for (int msk = 1; msk < 16; msk <<= 1) ssum += __shfl_xor(ssum, msk, 64);
            float rinv = 1.0f / ssum;
#pragma unroll
            for (int nt = 0; nt < 4; nt++) sw[row * 72 + nt * 16 + l15] = f2bf(e[nt] * rinv);
        }
    }
    bf16x8 pf[2][4];
#pragma unroll
    for (int kc2 = 0; kc2 < 2; kc2++)
#pragma unroll
        for (int mt = 0; mt < 4; mt++)
            pf[kc2][mt] = *(const bf16x8*)(sw + (mt * 16 + l15) * 72 + kc2 * 32 + qd * 8);

    // ---- V^T repack (accV + bias) -> scr [d][s] -> vf ----
#pragma unroll
    for (int mt = 0; mt < 4; mt++)
#pragma unroll
        for (int nt = 0; nt < 4; nt++) {
            int d = nt * 16 + l15;
            float bb = bv[w * 64 + d];
            ushort4 pk;
            pk.x = f2bf(accV[mt][nt][0] + bb);
            pk.y = f2bf(accV[mt][nt][1] + bb);
            pk.z = f2bf(accV[mt][nt][2] + bb);
            pk.w = f2bf(accV[mt][nt][3] + bb);
            *(ushort4*)(sw + d * 72 + mt * 16 + qd * 4) = pk;
        }
    bf16x8 vf[2][4];
#pragma unroll
    for (int kc2 = 0; kc2 < 2; kc2++)
#pragma unroll
        for (int nt = 0; nt < 4; nt++)
            vf[kc2][nt] = *(const bf16x8*)(sw + (nt * 16 + l15) * 72 + kc2 * 32 + qd * 8);

    // ---- O = P @ V ----
    f32x4 acc[4][4];
#pragma unroll
    for (int mt = 0; mt < 4; mt++)
#pragma unroll
        for (int nt = 0; nt < 4; nt++) acc[mt][nt] = zero4;
#pragma unroll
    for (int kc2 = 0; kc2 < 2; kc2++)
#pragma unroll
        for (int nt = 0; nt < 4; nt++)
#pragma unroll
            for (int mt = 0; mt < 4; mt++)
                acc[mt][nt] = __builtin_amdgcn_mfma_f32_16x16x32_bf16(pf[kc2][mt], vf[kc2][nt], acc[mt][nt], 0, 0, 0);

    // ---- O head -> scratch [q][d] bf16 ----
#pragma unroll
    for (int mt = 0; mt < 4; mt++)
#pragma unroll
        for (int nt = 0; nt < 4; nt++)
#pragma unroll
            for (int r = 0; r < 4; r++)
                sw[(mt * 16 + qd * 4 + r) * 72 + nt * 16 + l15] = f2bf(acc[mt][nt][r]);
    __syncthreads();

    // ---- Wo gemm: out cols w*64..; A = O concat (from 4 scratches), B = Wo rows ----
    {
        const u16* WO = Wt + 3 * 65536 + (size_t)(w * 64) * 256;
#pragma unroll
        for (int mt = 0; mt < 4; mt++)
#pragma unroll
            for (int nt = 0; nt < 4; nt++) acc[mt][nt] = zero4;
#pragma unroll
        for (int kc = 0; kc < 8; kc++) {
            int h = kc >> 1, k2 = kc & 1;
            bf16x8 af[4], bfr[4];
#pragma unroll
            for (int mt = 0; mt < 4; mt++)
                af[mt] = *(const bf16x8*)(&scr[h][mt * 16 + l15][k2 * 32 + qd * 8]);
#pragma unroll
            for (int nt = 0; nt < 4; nt++)
                bfr[nt] = *(const bf16x8*)(WO + (size_t)(nt * 16 + l15) * 256 + kc * 32 + qd * 8);
#pragma unroll
            for (int mt = 0; mt < 4; mt++)
#pragma unroll
                for (int nt = 0; nt < 4; nt++)
                    acc[mt][nt] = __builtin_amdgcn_mfma_f32_16x16x32_bf16(af[mt], bfr[nt], acc[mt][nt], 0, 0, 0);
        }
    }

    // ---- epilogue: +bias +residual (xs LDS), scratch-free grouped max, write clus ----
#pragma unroll
    for (int mt = 0; mt < 4; mt++)
#pragma unroll
        for (int nt = 0; nt < 4; nt++) {
            int col = w * 64 + nt * 16 + l15;
            float bb = bo[col];
#pragma unroll
            for (int r = 0; r < 4; r++) {
                int s = mt * 16 + qd * 4 + r;
                acc[mt][nt][r] += bb + bf2f(xs[s][col]);
            }
        }
    int myidx = sidx[lane];
    u32 sr0 = 0, sr1 = 0;
#pragma unroll
    for (int mt = 0; mt < 4; mt++)
#pragma unroll
        for (int r = 0; r < 4; r++) {
            int idx = mt * 4 + r;
            u32 v = (u32)sidx[mt * 16 + qd * 4 + r];
            if (idx < 8) sr0 |= v << (idx * 4); else sr1 |= v << ((idx - 8) * 4);
        }
    size_t ob = ((size_t)(pp * 64 + nn)) * 1024;
#pragma unroll
    for (int k = 0; k < 4; k++) {
        unsigned long long bal = __ballot(myidx == k);
        int ck = __popcll(bal);
        float m0 = FMIN32, m1 = FMIN32, m2 = FMIN32, m3 = FMIN32;
#pragma unroll
        for (int mt = 0; mt < 4; mt++)
#pragma unroll
            for (int r = 0; r < 4; r++) {
                int idx = mt * 4 + r;
                u32 kk = ((idx < 8 ? sr0 : sr1) >> ((idx & 7) * 4)) & 15u;
                bool tk = (kk == (u32)k);
                m0 = tk ? fmaxf(m0, acc[mt][0][r]) : m0;
                m1 = tk ? fmaxf(m1, acc[mt][1][r]) : m1;
                m2 = tk ? fmaxf(m2, acc[mt][2][r]) : m2;
                m3 = tk ? fmaxf(m3, acc[mt][3][r]) : m3;
            }
        float mm[4] = {m0, m1, m2, m3};
#pragma unroll
        for (int nt = 0; nt < 4; nt++) {
            float m = mm[nt];
            m = fmaxf(m, __shfl_xor(m, 16, 64));
            m = fmaxf(m, __shfl_xor(m, 32, 64));
            if (ck < 64) m = fmaxf(m, 0.0f);
            if (qd == 0) clus[ob + k * 256 + w * 64 + nt * 16 + l15] = f2bf(m);
        }
    }
}

// ======== gemm_fc (blk 0..255) | cluster_mode (blk 256..271) — one launch ========
__global__ __launch_bounds__(256) void gemm_fc_cm(const u16* clus, const u16* fcT, float* part,
                                                  const int* hard, float* outp) {
    __shared__ u16 As[64 * 32];
    __shared__ u16 Bs[64 * 32];
    int blk = blockIdx.x;
    int t = threadIdx.x;
    if (blk >= 256) {
        // ---- cluster_mode: mode over parts -> cluster_indices (fp32 out) ----
        int tid = (blk - 256) * 256 + t;
        int nn = tid >> 6, s = tid & 63;
        int cnt[4] = {0, 0, 0, 0};
#pragma unroll
        for (int p = 0; p < 16; p++) cnt[hard[((p * 64 + nn) << 6) + s]]++;
        int best = 0;
#pragma unroll
        for (int k = 1; k < 4; k++) if (cnt[k] > cnt[best]) best = k;
        outp[tid] = (float)best;
        return;
    }
    // ---- MFMA SeparateFCs, K-split: partial[kz][n][o][p] over kz chunks of 256 ----
    int p = blk & 15, by = (blk >> 4) & 3, kz = blk >> 6;
    const u16* Ap = clus + (size_t)p * 65536 + kz * 256;
    const u16* Bp = fcT + (size_t)p * 262144 + (size_t)(by * 64) * 1024 + kz * 256;
    int w = t >> 6, lane = t & 63;
    int l15 = lane & 15, qd = lane >> 4;
    f32x4 acc[4] = {};
    int srow = t >> 2, scg = t & 3;
    for (int kc = 0; kc < 256; kc += 32) {
        *(uint4*)(As + srow * 32 + scg * 8) =
            *(const uint4*)(Ap + (size_t)srow * 1024 + kc + scg * 8);
        *(uint4*)(Bs + srow * 32 + scg * 8) =
            *(const uint4*)(Bp + (size_t)srow * 1024 + kc + scg * 8);
        __syncthreads();
        bf16x8 bfr = *(const bf16x8*)(Bs + (w * 16 + l15) * 32 + qd * 8);
#pragma unroll
        for (int mt = 0; mt < 4; mt++) {
            bf16x8 af = *(const bf16x8*)(As + (mt * 16 + l15) * 32 + qd * 8);
            acc[mt] = __builtin_amdgcn_mfma_f32_16x16x32_bf16(af, bfr, acc[mt], 0, 0, 0);
        }
        __syncthreads();
    }
#pragma unroll
    for (int mt = 0; mt < 4; mt++)
#pragma unroll
        for (int r = 0; r < 4; r++) {
            int n = mt * 16 + qd * 4 + r;
            int o = by * 64 + w * 16 + l15;
            part[(size_t)kz * 262144 + (size_t)n * 4096 + (size_t)o * 16 + p] = acc[mt][r];
        }
}

// ---- sum 4 K-partials -> out_fc (float4 vectorized) ----
__global__ __launch_bounds__(256) void reduce_fc(const float* part, float* out) {
    int tid = blockIdx.x * 256 + threadIdx.x;
    const float4* p0 = (const float4*)part;
    float4 a = p0[tid];
    float4 b = p0[65536 + tid];
    float4 c = p0[131072 + tid];
    float4 d = p0[196608 + tid];
    float4 r;
    r.x = a.x + b.x + c.x + d.x;
    r.y = a.y + b.y + c.y + d.y;
    r.z = a.z + b.z + c.z + d.z;
    r.w = a.w + b.w + c.w + d.w;
    ((float4*)out)[tid] = r;
}

extern "C" void kernel_launch(void* const* d_in, const int* in_sizes, int n_in,
                              void* d_out, int out_size, void* d_ws, size_t ws_size,
                              hipStream_t stream) {
    const float* x    = (const float*)d_in[0];
    const float* prot = (const float*)d_in[1];
    const float* Wq   = (const float*)d_in[2];
    const float* bq   = (const float*)d_in[3];
    const float* Wk   = (const float*)d_in[4];
    const float* bk   = (const float*)d_in[5];
    const float* Wv   = (const float*)d_in[6];
    const float* bv   = (const float*)d_in[7];
    const float* Wo   = (const float*)d_in[8];
    const float* bo   = (const float*)d_in[9];
    const float* fcb  = (const float*)d_in[10];

    // Workspace map:
    //   [0,      33.5M)  xtbf bf16
    //   [33.5M, 100.7M)  xt fp32 (dead after norm_sim) -> fcpart (4 MB) reuses this
    //   [134.2M,+0.5M )  Wt bf16
    //   [134.7M,+8.4M )  fcT bf16
    //   [143.1M,+0.26M)  hard int32
    //   [143.4M,+2.1M )  clus bf16
    char* ws = (char*)d_ws;
    u16*   xtbf = (u16*)(ws + 0);
    float* xt   = (float*)(ws + 33554432);
    float* fcpart = (float*)(ws + 33554432);
    u16*   Wt   = (u16*)(ws + 134217728);
    u16*   fcT  = (u16*)(ws + 134742016);
    int*   hard = (int*)(ws + 143130624);
    u16*   clus = (u16*)(ws + 143392768);

    float* out_fc = (float*)d_out;
    float* out_ci = (float*)d_out + 262144;

    dim3 B(256);
    prep<<<dim3(6400), B, 0, stream>>>(x, xt, xtbf, Wq, Wk, Wv, Wo, Wt, fcb, fcT);
    norm_sim<<<dim3(1024), B, 0, stream>>>(xt, prot, hard);
    fused_attn<<<dim3(1024), B, 0, stream>>>(xtbf, Wt, bq, bk, bv, bo, hard, clus);
    gemm_fc_cm<<<dim3(272), B, 0, stream>>>(clus, fcT, fcpart, hard, out_ci);
    reduce_fc<<<dim3(256), B, 0, stream>>>(fcpart, out_fc);
}